// Round 1
// 70.570 us; speedup vs baseline: 1.1096x; 1.1096x over previous
//
#include <hip/hip_runtime.h>

#define BLOCK 512               // 8 waves/block
#define IPT   4                 // i-values per thread
#define ITILE 2048              // BLOCK*IPT rows per tile
#define JS    128               // j-columns per tile
#define NBI   8                 // N / ITILE
#define NBJ   128               // N / JS
#define NT    (NBI * NBJ)       // 1024 blocks: FULL matrix, no weights
#define RBLOCK 1024

typedef _Float16 h2 __attribute__((ext_vector_type(2)));

// R15: algebraic 3-op inner loop + full-matrix tiling.
//
// clip(x,-1,1) = 2*clamp(x/2+0.5, 0, 1) - 1, and clamp is the FREE [0,1]
// output modifier on v_pk_add_f16. Stage j as B_j = 0.5-0.5*x_j, keep i as
// A_i = 0.5*x_i, so y = clamp(A_i + B_j) is ONE packed add (inline asm pins
// the clamp fold). Complement identity y(i,j)+y(j,i)=1 => sum_full y = N^2/2
// analytically, so over the FULL N^2 matrix:
//     S = sum clip(pd)*clip(td) = 4*sum(yp*yt) - N^2
// -> per 2 pairs: 2x v_pk_add_f16 clamp + 1x v_dot2_f32_f16 (3 VALU, was 7).
// Full matrix = 1.34e8 packets * 3 = 4.03e8 VALU (was 0.76e8*7 = 5.29e8,
// -24%), grid 576->1024 blocks (8 waves/SIMD, 4 blocks/CU exactly), and the
// sqrt triangular decode + tile weights are gone.
//
// Ledger context: 39.6us poison fill (untouchable) + ~33us pairs wall
// (invariant to SCHEDULING structure; this probes instruction count + TLP
// instead) + ~4us launch. If this lands at ~78us, the wall is a clock/latency
// floor -> roofline.
__global__ __launch_bounds__(BLOCK, 8) void kendall_pairs(
    const float* __restrict__ p, const float* __restrict__ t,
    float* __restrict__ partial, int n) {
    __shared__ unsigned int sjp[JS / 2];         // packed (B_j0,B_j1) half2
    __shared__ unsigned int sjt[JS / 2];

    const int bi = blockIdx.x >> 7;              // / NBJ
    const int bj = blockIdx.x & (NBJ - 1);

    // stage j-slice pre-transformed: B_j = 0.5 - 0.5*x_j (half2 packed)
    if (threadIdx.x < JS) {
        const int k = threadIdx.x & 63;
        const float2* src = (const float2*)((threadIdx.x < 64 ? p : t) + bj * JS);
        float2 v = src[k];
        h2 hv = {(_Float16)(0.5f - 0.5f * v.x), (_Float16)(0.5f - 0.5f * v.y)};
        unsigned int bitsv; __builtin_memcpy(&bitsv, &hv, 4);
        (threadIdx.x < 64 ? sjp : sjt)[k] = bitsv;
    }

    // i-values: A_i = 0.5*x_i splat to (A,A) half2
    h2 pi2[IPT], ti2[IPT];
#pragma unroll
    for (int u = 0; u < IPT; ++u) {
        int i = bi * ITILE + u * BLOCK + threadIdx.x;   // coalesced; n=16384 exact
        _Float16 ph = (_Float16)(0.5f * p[i]);
        _Float16 th = (_Float16)(0.5f * t[i]);
        pi2[u] = (h2){ph, ph};
        ti2[u] = (h2){th, th};
    }
    __syncthreads();

    float acc[IPT] = {0.0f};                     // 4 independent dot2 chains
    const uint4* jp4 = (const uint4*)sjp;        // 1 b128 = 4 half2 = 8 j's
    const uint4* jt4 = (const uint4*)sjt;

#pragma unroll 4
    for (int g = 0; g < JS / 8; ++g) {           // 16 groups of 8 j's
        uint4 jp = jp4[g];                       // uniform addr -> LDS broadcast
        uint4 jt = jt4[g];
        unsigned int jpw[4] = {jp.x, jp.y, jp.z, jp.w};
        unsigned int jtw[4] = {jt.x, jt.y, jt.z, jt.w};
#pragma unroll
        for (int c = 0; c < 4; ++c) {
            h2 pj, tj;
            __builtin_memcpy(&pj, &jpw[c], 4);
            __builtin_memcpy(&tj, &jtw[c], 4);
#pragma unroll
            for (int u = 0; u < IPT; ++u) {
                h2 yp, yt;                       // y = clamp(A_i + B_j) in [0,1]
                asm("v_pk_add_f16 %0, %1, %2 clamp" : "=v"(yp) : "v"(pi2[u]), "v"(pj));
                asm("v_pk_add_f16 %0, %1, %2 clamp" : "=v"(yt) : "v"(ti2[u]), "v"(tj));
                acc[u] = __builtin_amdgcn_fdot2(yp, yt, acc[u], false);
            }
        }
    }

    float r = (acc[0] + acc[1]) + (acc[2] + acc[3]);
#pragma unroll
    for (int off = 32; off > 0; off >>= 1) r += __shfl_down(r, off, 64);

    if ((threadIdx.x & 63) == 0)                 // one store/wave; no 2nd barrier
        partial[blockIdx.x * (BLOCK / 64) + (threadIdx.x >> 6)] = r;
}

// One block: reduce nPartial floats (L2-resident) -> S = 4*A - N^2 -> loss.
__global__ __launch_bounds__(RBLOCK) void kendall_reduce(
    const float* __restrict__ partial, float* __restrict__ out,
    int nPartial, int n) {
    __shared__ float wsum[RBLOCK / 64];
    float s = 0.0f;
    for (int k = threadIdx.x; k < nPartial; k += RBLOCK) s += partial[k];
#pragma unroll
    for (int off = 32; off > 0; off >>= 1) s += __shfl_down(s, off, 64);
    const int lane = threadIdx.x & 63;
    const int wid  = threadIdx.x >> 6;
    if (lane == 0) wsum[wid] = s;
    __syncthreads();
    if (threadIdx.x == 0) {
        float A = 0.0f;
#pragma unroll
        for (int v2 = 0; v2 < RBLOCK / 64; ++v2) A += wsum[v2];
        float nf = (float)n;
        float S = 4.0f * A - nf * nf;            // analytic sum_y substitution
        float denom = nf * (float)(n - 1);
        out[0] = 1.0f - S / denom;
    }
}

extern "C" void kernel_launch(void* const* d_in, const int* in_sizes, int n_in,
                              void* d_out, int out_size, void* d_ws, size_t ws_size,
                              hipStream_t stream) {
    const float* predict = (const float*)d_in[0];
    const float* target  = (const float*)d_in[1];
    float* out = (float*)d_out;
    float* partial = (float*)d_ws;               // NT*8 slots, all written each call
    const int n = in_sizes[0];                   // 16384

    const int nPartial = NT * (BLOCK / 64);      // 8192
    kendall_pairs<<<NT, BLOCK, 0, stream>>>(predict, target, partial, n);
    kendall_reduce<<<1, RBLOCK, 0, stream>>>(partial, out, nPartial, n);
}

// Round 2
// 69.977 us; speedup vs baseline: 1.1190x; 1.0085x over previous
//
#include <hip/hip_runtime.h>

#define BLOCK 512               // 8 waves/block
#define NIB   64                // i-blocks of 256 i's
#define NJB   16                // j-blocks of 1024 j's
#define NT    (NIB * NJB)       // 1024 blocks, FULL matrix
#define IBS   256               // i's per block (8 waves x 32)
#define JBS   1024              // j's per block
#define RBLOCK 1024

typedef _Float16 h2 __attribute__((ext_vector_type(2)));
typedef _Float16 h4 __attribute__((ext_vector_type(4)));
typedef _Float16 h8 __attribute__((ext_vector_type(8)));
typedef float    f4 __attribute__((ext_vector_type(4)));

// R16: move the product stage onto the MFMA pipe.
//
// y = clamp(A_i + B_j) (one v_pk_add_f16 clamp, as R15; S = 4*sum(yp*yt)-N^2).
// Wave computes yp/yt directly in v_mfma_f32_16x16x32_f16 fragment layout:
//   lane l: j = jbase + (l&15)  (M/N index),  i = ibase + 8*(l>>4) + e (K).
// A-frag = yp, B-frag = yt over the SAME (j,i) set -> diag(D) = sum_i yp*yt
// for 16 j x 32 i = 512 pairs/MFMA (vs 128/dot2), product on the MFMA pipe.
// j-broadcast uses VOP3P op_sel half-select (no splat op). i-halves live in
// 4 regs/operand. B-values staged in LDS swizzled so one ds_read_b128 feeds
// 8 j-steps. Per 512 pairs: 8 pk_add + 1 MFMA + 0.25 ds (was 12 VALU).
// Correctness is layout-robust: k-permutations/m-relabelings cancel if A/B
// frags are mirror-symmetric; D extraction uses verified col=lane&15,
// row=4*(lane>>4)+reg. Two interleaved accs relax the MFMA dep chain.
//
// Ledger: 39.6us poison fill (untouchable) + pairs wall (proven ~cycle-
// proportional in R15: -24% VALU -> -21% wall) + ~4us launch.

__device__ __forceinline__ h2 addclamp_lo(h2 a, unsigned int b) {
    h2 r;  // low result: a.lo + b.lo ; high result: a.hi + b.lo  (broadcast b.lo)
    asm("v_pk_add_f16 %0, %1, %2 op_sel_hi:[1,0] clamp" : "=v"(r) : "v"(a), "v"(b));
    return r;
}
__device__ __forceinline__ h2 addclamp_hi(h2 a, unsigned int b) {
    h2 r;  // broadcast b.hi to both halves
    asm("v_pk_add_f16 %0, %1, %2 op_sel:[0,1] op_sel_hi:[1,1] clamp" : "=v"(r) : "v"(a), "v"(b));
    return r;
}
__device__ __forceinline__ h8 cat8(h2 y0, h2 y1, h2 y2, h2 y3) {
    h4 lo = __builtin_shufflevector(y0, y1, 0, 1, 2, 3);
    h4 hi = __builtin_shufflevector(y2, y3, 0, 1, 2, 3);
    return __builtin_shufflevector(lo, hi, 0, 1, 2, 3, 4, 5, 6, 7);
}
__device__ __forceinline__ h8 fraglo(h2 a0, h2 a1, h2 a2, h2 a3, unsigned int b) {
    return cat8(addclamp_lo(a0, b), addclamp_lo(a1, b), addclamp_lo(a2, b), addclamp_lo(a3, b));
}
__device__ __forceinline__ h8 fraghi(h2 a0, h2 a1, h2 a2, h2 a3, unsigned int b) {
    return cat8(addclamp_hi(a0, b), addclamp_hi(a1, b), addclamp_hi(a2, b), addclamp_hi(a3, b));
}

// swizzled LDS index: within each 128-j chunk, value for j = 16*s + m lands at
// halfword m*8 + s, so lane m's 8 step-values are one contiguous b128.
__device__ __forceinline__ int bidx(int j) {
    return ((j >> 7) << 7) | ((j & 15) << 3) | ((j >> 4) & 7);
}

__global__ __launch_bounds__(BLOCK, 8) void kendall_pairs(
    const float* __restrict__ p, const float* __restrict__ t,
    float* __restrict__ partial, int n) {
    __shared__ unsigned short sb[2 * JBS];   // [0,1024): Bp swizzled; [1024,2048): Bt

    const int tid  = threadIdx.x;
    const int w    = tid >> 6, lane = tid & 63, g = lane >> 4, m = lane & 15;
    const int ibB  = ((int)blockIdx.x >> 4) * IBS;   // i-block base
    const int jbase = ((int)blockIdx.x & 15) * JBS;  // j-block base

    // stage B = 0.5 - 0.5*x for 1024 j's (both operands), f16, swizzled
    {
        const int j0 = 2 * tid;
        float2 pv = *(const float2*)(p + jbase + j0);
        float2 tv = *(const float2*)(t + jbase + j0);
        const int i0 = bidx(j0), i1 = bidx(j0 + 1);
        _Float16 v;
        unsigned short u;
        v = (_Float16)(0.5f - 0.5f * pv.x); __builtin_memcpy(&u, &v, 2); sb[i0] = u;
        v = (_Float16)(0.5f - 0.5f * pv.y); __builtin_memcpy(&u, &v, 2); sb[i1] = u;
        v = (_Float16)(0.5f - 0.5f * tv.x); __builtin_memcpy(&u, &v, 2); sb[JBS + i0] = u;
        v = (_Float16)(0.5f - 0.5f * tv.y); __builtin_memcpy(&u, &v, 2); sb[JBS + i1] = u;
    }

    // A-side: 8 consecutive i's per lane (K-slice), transformed 0.5*x, half2 pairs
    const int ibase = ibB + w * 32 + g * 8;
    float4 pa = *(const float4*)(p + ibase);
    float4 pb = *(const float4*)(p + ibase + 4);
    float4 ta = *(const float4*)(t + ibase);
    float4 tb = *(const float4*)(t + ibase + 4);
    h2 ap0 = {(_Float16)(0.5f * pa.x), (_Float16)(0.5f * pa.y)};
    h2 ap1 = {(_Float16)(0.5f * pa.z), (_Float16)(0.5f * pa.w)};
    h2 ap2 = {(_Float16)(0.5f * pb.x), (_Float16)(0.5f * pb.y)};
    h2 ap3 = {(_Float16)(0.5f * pb.z), (_Float16)(0.5f * pb.w)};
    h2 at0 = {(_Float16)(0.5f * ta.x), (_Float16)(0.5f * ta.y)};
    h2 at1 = {(_Float16)(0.5f * ta.z), (_Float16)(0.5f * ta.w)};
    h2 at2 = {(_Float16)(0.5f * tb.x), (_Float16)(0.5f * tb.y)};
    h2 at3 = {(_Float16)(0.5f * tb.z), (_Float16)(0.5f * tb.w)};
    __syncthreads();

    f4 accA = {0.f, 0.f, 0.f, 0.f};
    f4 accB = {0.f, 0.f, 0.f, 0.f};
    const uint4* bp4 = (const uint4*)sb;           // 128 quads of Bp
    const uint4* bt4 = (const uint4*)(sb + JBS);   // 128 quads of Bt

#pragma unroll
    for (int c = 0; c < 8; ++c) {                  // 8 chunks of 128 j's
        uint4 qp = bp4[c * 16 + m];                // lane m's 8 Bp step-values
        uint4 qt = bt4[c * 16 + m];
        unsigned int pw[4] = {qp.x, qp.y, qp.z, qp.w};
        unsigned int tw[4] = {qt.x, qt.y, qt.z, qt.w};
#pragma unroll
        for (int q = 0; q < 4; ++q) {              // 2 j-steps per word (lo/hi half)
            accA = __builtin_amdgcn_mfma_f32_16x16x32_f16(
                fraglo(ap0, ap1, ap2, ap3, pw[q]),
                fraglo(at0, at1, at2, at3, tw[q]), accA, 0, 0, 0);
            accB = __builtin_amdgcn_mfma_f32_16x16x32_f16(
                fraghi(ap0, ap1, ap2, ap3, pw[q]),
                fraghi(at0, at1, at2, at3, tw[q]), accB, 0, 0, 0);
        }
    }

    // diag(D): C/D layout col=lane&15, row=4*(lane>>4)+reg  ->  reg r = m-4g
    f4 acc = accA + accB;
    const int r = m - 4 * g;
    float d = 0.f;
    if      (r == 0) d = acc[0];
    else if (r == 1) d = acc[1];
    else if (r == 2) d = acc[2];
    else if (r == 3) d = acc[3];
#pragma unroll
    for (int off = 32; off > 0; off >>= 1) d += __shfl_down(d, off, 64);
    if (lane == 0) partial[blockIdx.x * (BLOCK / 64) + w] = d;
}

// One block: reduce nPartial floats (L2-resident) -> S = 4*A - N^2 -> loss.
__global__ __launch_bounds__(RBLOCK) void kendall_reduce(
    const float* __restrict__ partial, float* __restrict__ out,
    int nPartial, int n) {
    __shared__ float wsum[RBLOCK / 64];
    float s = 0.0f;
    for (int k = threadIdx.x; k < nPartial; k += RBLOCK) s += partial[k];
#pragma unroll
    for (int off = 32; off > 0; off >>= 1) s += __shfl_down(s, off, 64);
    const int lane = threadIdx.x & 63;
    const int wid  = threadIdx.x >> 6;
    if (lane == 0) wsum[wid] = s;
    __syncthreads();
    if (threadIdx.x == 0) {
        float A = 0.0f;
#pragma unroll
        for (int v2 = 0; v2 < RBLOCK / 64; ++v2) A += wsum[v2];
        float nf = (float)n;
        float S = 4.0f * A - nf * nf;            // analytic sum_y substitution
        float denom = nf * (float)(n - 1);
        out[0] = 1.0f - S / denom;
    }
}

extern "C" void kernel_launch(void* const* d_in, const int* in_sizes, int n_in,
                              void* d_out, int out_size, void* d_ws, size_t ws_size,
                              hipStream_t stream) {
    const float* predict = (const float*)d_in[0];
    const float* target  = (const float*)d_in[1];
    float* out = (float*)d_out;
    float* partial = (float*)d_ws;               // NT*8 slots, all written each call
    const int n = in_sizes[0];                   // 16384

    const int nPartial = NT * (BLOCK / 64);      // 8192
    kendall_pairs<<<NT, BLOCK, 0, stream>>>(predict, target, partial, n);
    kendall_reduce<<<1, RBLOCK, 0, stream>>>(partial, out, nPartial, n);
}

// Round 3
// 69.287 us; speedup vs baseline: 1.1302x; 1.0100x over previous
//
#include <hip/hip_runtime.h>

#define BLOCK 512               // 8 waves/block
#define NIB   64                // i-blocks of 256 i's
#define NJB   16                // j-blocks of 1024 j's
#define NT    (NIB * NJB)       // 1024 blocks, FULL matrix
#define IBS   256               // i's per block (8 waves x 32)
#define JBS   1024              // j's per block
#define RBLOCK 1024

typedef _Float16 h2 __attribute__((ext_vector_type(2)));
typedef _Float16 h4 __attribute__((ext_vector_type(4)));
typedef _Float16 h8 __attribute__((ext_vector_type(8)));
typedef float    f4 __attribute__((ext_vector_type(4)));

// R17: balance VALU and MFMA pipes.
//
// Cycle model (R15/R16 post-mortem, f_eff ~473 MHz burst clock):
//   wall ~= max(VALU_cyc, MFMA_cyc) per SIMD.
//   R15: VALU 12288 / MFMA 0     -> 26us  (VALU-bound)
//   R16: VALU  8192 / MFMA 9932  -> 26us  (MFMA-bound: 16x16x32 f16 is
//        ~19.4 cyc per SIMD = 2075 TF / 1024 SIMDs; diagonal use = 1/16
//        of MACs, so the MFMA pipe became the new wall -> null result)
// Fix: per wave, 7 of 8 j-chunks go through MFMA (16 VALU + 19.4 MFMA per
// 512 pairs), 1 chunk (c == waveid, staggered) through the R15 dot2 path
// (24 VALU, 0 MFMA). Per wave: VALU 1088 cyc vs MFMA 1086 cyc -- both pipes
// saturated. dot2 path reuses the SAME swizzled LDS quads and i-registers
// (op_sel broadcast), zero extra loads.
//
// Math (unchanged from R15/R16): y = clamp(A_i + B_j), one v_pk_add_f16
// clamp; S = 4*sum_full(yp*yt) - N^2 via complement identity.
// Ledger: 39.6us poison fill (untouchable) + pairs wall + ~4.5us launch.

__device__ __forceinline__ h2 addclamp_lo(h2 a, unsigned int b) {
    h2 r;  // broadcast b.lo to both result halves
    asm("v_pk_add_f16 %0, %1, %2 op_sel_hi:[1,0] clamp" : "=v"(r) : "v"(a), "v"(b));
    return r;
}
__device__ __forceinline__ h2 addclamp_hi(h2 a, unsigned int b) {
    h2 r;  // broadcast b.hi to both result halves
    asm("v_pk_add_f16 %0, %1, %2 op_sel:[0,1] op_sel_hi:[1,1] clamp" : "=v"(r) : "v"(a), "v"(b));
    return r;
}
__device__ __forceinline__ h8 cat8(h2 y0, h2 y1, h2 y2, h2 y3) {
    h4 lo = __builtin_shufflevector(y0, y1, 0, 1, 2, 3);
    h4 hi = __builtin_shufflevector(y2, y3, 0, 1, 2, 3);
    return __builtin_shufflevector(lo, hi, 0, 1, 2, 3, 4, 5, 6, 7);
}
__device__ __forceinline__ h8 fraglo(h2 a0, h2 a1, h2 a2, h2 a3, unsigned int b) {
    return cat8(addclamp_lo(a0, b), addclamp_lo(a1, b), addclamp_lo(a2, b), addclamp_lo(a3, b));
}
__device__ __forceinline__ h8 fraghi(h2 a0, h2 a1, h2 a2, h2 a3, unsigned int b) {
    return cat8(addclamp_hi(a0, b), addclamp_hi(a1, b), addclamp_hi(a2, b), addclamp_hi(a3, b));
}

// swizzled LDS index: within each 128-j chunk, value for j = 16*s + m lands at
// halfword m*8 + s, so lane m's 8 step-values are one contiguous b128.
__device__ __forceinline__ int bidx(int j) {
    return ((j >> 7) << 7) | ((j & 15) << 3) | ((j >> 4) & 7);
}

__global__ __launch_bounds__(BLOCK, 6) void kendall_pairs(
    const float* __restrict__ p, const float* __restrict__ t,
    float* __restrict__ partial, int n) {
    __shared__ unsigned short sb[2 * JBS];   // [0,1024): Bp swizzled; [1024,2048): Bt

    const int tid  = threadIdx.x;
    const int w    = tid >> 6, lane = tid & 63, g = lane >> 4, m = lane & 15;
    const int ibB  = ((int)blockIdx.x >> 4) * IBS;   // i-block base
    const int jbase = ((int)blockIdx.x & 15) * JBS;  // j-block base

    // stage B = 0.5 - 0.5*x for 1024 j's (both operands), f16, swizzled
    {
        const int j0 = 2 * tid;
        float2 pv = *(const float2*)(p + jbase + j0);
        float2 tv = *(const float2*)(t + jbase + j0);
        const int i0 = bidx(j0), i1 = bidx(j0 + 1);
        _Float16 v;
        unsigned short u;
        v = (_Float16)(0.5f - 0.5f * pv.x); __builtin_memcpy(&u, &v, 2); sb[i0] = u;
        v = (_Float16)(0.5f - 0.5f * pv.y); __builtin_memcpy(&u, &v, 2); sb[i1] = u;
        v = (_Float16)(0.5f - 0.5f * tv.x); __builtin_memcpy(&u, &v, 2); sb[JBS + i0] = u;
        v = (_Float16)(0.5f - 0.5f * tv.y); __builtin_memcpy(&u, &v, 2); sb[JBS + i1] = u;
    }

    // A-side: 8 consecutive i's per lane (K-slice), transformed 0.5*x, half2 pairs
    const int ibase = ibB + w * 32 + g * 8;
    float4 pa = *(const float4*)(p + ibase);
    float4 pb = *(const float4*)(p + ibase + 4);
    float4 ta = *(const float4*)(t + ibase);
    float4 tb = *(const float4*)(t + ibase + 4);
    h2 ap0 = {(_Float16)(0.5f * pa.x), (_Float16)(0.5f * pa.y)};
    h2 ap1 = {(_Float16)(0.5f * pa.z), (_Float16)(0.5f * pa.w)};
    h2 ap2 = {(_Float16)(0.5f * pb.x), (_Float16)(0.5f * pb.y)};
    h2 ap3 = {(_Float16)(0.5f * pb.z), (_Float16)(0.5f * pb.w)};
    h2 at0 = {(_Float16)(0.5f * ta.x), (_Float16)(0.5f * ta.y)};
    h2 at1 = {(_Float16)(0.5f * ta.z), (_Float16)(0.5f * ta.w)};
    h2 at2 = {(_Float16)(0.5f * tb.x), (_Float16)(0.5f * tb.y)};
    h2 at3 = {(_Float16)(0.5f * tb.z), (_Float16)(0.5f * tb.w)};
    __syncthreads();

    f4 accA = {0.f, 0.f, 0.f, 0.f};
    f4 accB = {0.f, 0.f, 0.f, 0.f};
    float accD0 = 0.f, accD1 = 0.f, accD2 = 0.f, accD3 = 0.f;
    const uint4* bp4 = (const uint4*)sb;           // 128 quads of Bp
    const uint4* bt4 = (const uint4*)(sb + JBS);   // 128 quads of Bt

#pragma unroll
    for (int c = 0; c < 8; ++c) {                  // 8 chunks of 128 j's
        uint4 qp = bp4[c * 16 + m];                // lane m's 8 Bp step-values
        uint4 qt = bt4[c * 16 + m];
        unsigned int pw[4] = {qp.x, qp.y, qp.z, qp.w};
        unsigned int tw[4] = {qt.x, qt.y, qt.z, qt.w};
        if (c == w) {
            // dot2 path (VALU only): per word, 2 j's; per j: 4 yp + 4 yt + 4 dot2
#pragma unroll
            for (int q = 0; q < 4; ++q) {
                accD0 = __builtin_amdgcn_fdot2(addclamp_lo(ap0, pw[q]), addclamp_lo(at0, tw[q]), accD0, false);
                accD1 = __builtin_amdgcn_fdot2(addclamp_lo(ap1, pw[q]), addclamp_lo(at1, tw[q]), accD1, false);
                accD2 = __builtin_amdgcn_fdot2(addclamp_lo(ap2, pw[q]), addclamp_lo(at2, tw[q]), accD2, false);
                accD3 = __builtin_amdgcn_fdot2(addclamp_lo(ap3, pw[q]), addclamp_lo(at3, tw[q]), accD3, false);
                accD0 = __builtin_amdgcn_fdot2(addclamp_hi(ap0, pw[q]), addclamp_hi(at0, tw[q]), accD0, false);
                accD1 = __builtin_amdgcn_fdot2(addclamp_hi(ap1, pw[q]), addclamp_hi(at1, tw[q]), accD1, false);
                accD2 = __builtin_amdgcn_fdot2(addclamp_hi(ap2, pw[q]), addclamp_hi(at2, tw[q]), accD2, false);
                accD3 = __builtin_amdgcn_fdot2(addclamp_hi(ap3, pw[q]), addclamp_hi(at3, tw[q]), accD3, false);
            }
        } else {
            // MFMA path: 2 j's per word (lo/hi half), diag(D) used
#pragma unroll
            for (int q = 0; q < 4; ++q) {
                accA = __builtin_amdgcn_mfma_f32_16x16x32_f16(
                    fraglo(ap0, ap1, ap2, ap3, pw[q]),
                    fraglo(at0, at1, at2, at3, tw[q]), accA, 0, 0, 0);
                accB = __builtin_amdgcn_mfma_f32_16x16x32_f16(
                    fraghi(ap0, ap1, ap2, ap3, pw[q]),
                    fraghi(at0, at1, at2, at3, tw[q]), accB, 0, 0, 0);
            }
        }
    }

    // diag(D): C/D layout col=lane&15, row=4*(lane>>4)+reg  ->  reg r = m-4g
    f4 acc = accA + accB;
    const int r = m - 4 * g;
    float d = (accD0 + accD1) + (accD2 + accD3);
    if      (r == 0) d += acc[0];
    else if (r == 1) d += acc[1];
    else if (r == 2) d += acc[2];
    else if (r == 3) d += acc[3];
#pragma unroll
    for (int off = 32; off > 0; off >>= 1) d += __shfl_down(d, off, 64);
    if (lane == 0) partial[blockIdx.x * (BLOCK / 64) + w] = d;
}

// One block: reduce nPartial floats (L2-resident) -> S = 4*A - N^2 -> loss.
__global__ __launch_bounds__(RBLOCK) void kendall_reduce(
    const float* __restrict__ partial, float* __restrict__ out,
    int nPartial, int n) {
    __shared__ float wsum[RBLOCK / 64];
    float s = 0.0f;
    for (int k = threadIdx.x; k < nPartial; k += RBLOCK) s += partial[k];
#pragma unroll
    for (int off = 32; off > 0; off >>= 1) s += __shfl_down(s, off, 64);
    const int lane = threadIdx.x & 63;
    const int wid  = threadIdx.x >> 6;
    if (lane == 0) wsum[wid] = s;
    __syncthreads();
    if (threadIdx.x == 0) {
        float A = 0.0f;
#pragma unroll
        for (int v2 = 0; v2 < RBLOCK / 64; ++v2) A += wsum[v2];
        float nf = (float)n;
        float S = 4.0f * A - nf * nf;            // analytic sum_y substitution
        float denom = nf * (float)(n - 1);
        out[0] = 1.0f - S / denom;
    }
}

extern "C" void kernel_launch(void* const* d_in, const int* in_sizes, int n_in,
                              void* d_out, int out_size, void* d_ws, size_t ws_size,
                              hipStream_t stream) {
    const float* predict = (const float*)d_in[0];
    const float* target  = (const float*)d_in[1];
    float* out = (float*)d_out;
    float* partial = (float*)d_ws;               // NT*8 slots, all written each call
    const int n = in_sizes[0];                   // 16384

    const int nPartial = NT * (BLOCK / 64);      // 8192
    kendall_pairs<<<NT, BLOCK, 0, stream>>>(predict, target, partial, n);
    kendall_reduce<<<1, RBLOCK, 0, stream>>>(partial, out, nPartial, n);
}